// Round 16
// baseline (562.685 us; speedup 1.0000x reference)
//
#include <hip/hip_runtime.h>
#include <cstdint>

// ---------------- problem constants ----------------
constexpr int B_ = 2, S_ = 1024, D_ = 1024, DS_ = 320, NSLOT_ = 512;
constexpr int H_ = 4, CH_ = 5, DFF_ = 4096;
constexpr int HD_ = D_ / H_;      // 256
constexpr int CHD_ = DS_ / CH_;   // 64
constexpr int BS_ = B_ * S_;      // 2048
constexpr int BNS_ = B_ * NSLOT_; // 1024

typedef unsigned short u16;
typedef __attribute__((ext_vector_type(8))) short bf16x8;
typedef __attribute__((ext_vector_type(4))) float f32x4;
typedef __attribute__((ext_vector_type(4))) u16 u16x4;
typedef long long ll;

__device__ __forceinline__ u16 f2bf(float f) {
  unsigned u = __float_as_uint(f);
  return (u16)((u + 0x7FFFu + ((u >> 16) & 1u)) >> 16);  // RNE
}
__device__ __forceinline__ float bf2f(u16 h) { return __uint_as_float((unsigned)h << 16); }

__device__ __forceinline__ void gload16(const void* g, void* l) {
  __builtin_amdgcn_global_load_lds((const __attribute__((address_space(1))) void*)g,
                                   (__attribute__((address_space(3))) void*)l, 16, 0, 0);
}

// ---------------- bf16 MFMA GEMM: C[m,n] = sum_k A[m,k]*B[n,k] ----------------
// r16: SHRINK THE SYNC DOMAIN. BM=64, BN=64, BK=64, 256 thr (4 waves, 16 rows
// each). Double-buffered LDS 2 x 16KB = 32KB -> 5 blocks/CU = 5 waves/SIMD,
// FIVE independent barrier domains per CU (r6 showed TLP/decorrelation is the
// only lever that moves this kernel; 4-wave barriers converge faster too).
// Step: vmcnt(0) -> barrier -> stage(t+1) -> ds_read(t) -> MFMA -> lgkm(0).
// XOR-swizzled LDS as before (0 bank conflicts verified r3-r15).
// Epilogue: bias / rowscale(col-gated) / gelu / +addF residual; col-split
// normal vs transposed-bf16 outputs.
__global__ __launch_bounds__(256, 5)
void k_gemm(const u16* __restrict__ A, int lda, ll sA, ll sA2,
            const u16* __restrict__ Bp, int ldb, ll sB, ll sB2,
            float* __restrict__ outF, u16* __restrict__ outB,
            int ldc, ll sC, ll sC2,
            u16* __restrict__ outBT, int ldt, ll sT, ll sT2,
            int K, int zdiv, const float* __restrict__ bias,
            const float* __restrict__ rowscale, int rscfrom,
            const float* __restrict__ addF,
            int splitcol, int act)
{
  constexpr int ABYT = 64 * 128;    // 8 KB
  constexpr int BBYT = 64 * 128;    // 8 KB
  constexpr int BUF = ABYT + BBYT;  // 16 KB
  const int z = blockIdx.z, zb = z / zdiv, zr = z - zb * zdiv;
  A  += (ll)zb * sA + (ll)zr * sA2;
  Bp += (ll)zb * sB + (ll)zr * sB2;
  const ll cof = (ll)zb * sC + (ll)zr * sC2;
  const ll tof = (ll)zb * sT + (ll)zr * sT2;
  const int bm = blockIdx.y * 64, bn = blockIdx.x * 64;
  __shared__ __align__(16) char lds[2 * BUF];   // 32 KB
  const int tid = threadIdx.x;
  const int lane = tid & 63, wid = tid >> 6;
  const int rowb = wid * 16;                    // 4 waves x 16 rows

  f32x4 acc[4];
  const f32x4 fz = {0.f, 0.f, 0.f, 0.f};
  #pragma unroll
  for (int j = 0; j < 4; ++j) acc[j] = fz;

  // staging: thread t -> row t>>3 (32 rows/pass), granule t&7;
  // source granule ^= row&7; LDS dest linear (wave base + lane*16).
  const int trow = tid >> 3;
  const int tg   = ((tid & 7) ^ (trow & 7)) * 8;
  const u16* gA  = A + (ll)(bm + trow) * lda + tg;
  const u16* gA2 = gA + (ll)32 * lda;
  const u16* gB  = Bp + (ll)(bn + trow) * ldb + tg;
  const u16* gB2 = gB + (ll)32 * ldb;

  // fragment reads: row base + r, granule (4s+q) ^ (r&7)
  const int r = lane & 15, q = lane >> 4;
  const int c7 = r & 7;
  const int gs0 = ((q) ^ c7) << 4;
  const int gs1 = ((4 + q) ^ c7) << 4;
  const int aoff = (rowb + r) * 128;
  int boff[4];
  #pragma unroll
  for (int j = 0; j < 4; ++j) boff[j] = ABYT + (j * 16 + r) * 128;

  auto stage = [&](int buf, int it) {
    char* la = lds + buf * BUF + wid * 1024;   // 4KB/pass across 4 waves
    char* lb = la + ABYT;
    const int ko = it << 6;
    gload16(gA + ko, la);
    gload16(gA2 + ko, la + 4096);
    gload16(gB + ko, lb);
    gload16(gB2 + ko, lb + 4096);
  };

  const int nsteps = K >> 6;
  stage(0, 0);
  int bufp = 0;
  for (int it = 0; it < nsteps; ++it) {
    asm volatile("s_waitcnt vmcnt(0)" ::: "memory");   // tile t landed
    __builtin_amdgcn_s_barrier();
    __builtin_amdgcn_sched_barrier(0);
    if (it + 1 < nsteps) stage(bufp ^ 1, it + 1);      // WAR-safe (readers passed barrier)
    const char* pa = lds + bufp * BUF;
    #pragma unroll
    for (int s = 0; s < 2; ++s) {
      const int gso = s ? gs1 : gs0;
      bf16x8 af = *(const bf16x8*)(pa + aoff + gso);
      bf16x8 bv[4];
      #pragma unroll
      for (int j = 0; j < 4; ++j) bv[j] = *(const bf16x8*)(pa + boff[j] + gso);
      #pragma unroll
      for (int j = 0; j < 4; ++j)
        acc[j] = __builtin_amdgcn_mfma_f32_16x16x32_bf16(af, bv[j], acc[j], 0, 0, 0);
    }
    asm volatile("s_waitcnt lgkmcnt(0)" ::: "memory"); // reads of buf done
    __builtin_amdgcn_sched_barrier(0);
    bufp ^= 1;
  }

  const int fr = lane & 15, fq = lane >> 4;
  const int r0 = bm + rowb + fq * 4;
  #pragma unroll
  for (int j = 0; j < 4; ++j) {
    const int cn = bn + j * 16 + fr;
    const float bvv = bias ? bias[cn] : 0.f;
    const bool doRs = rowscale && (cn >= rscfrom);
    float vv[4];
    #pragma unroll
    for (int t = 0; t < 4; ++t) {
      float v = acc[j][t] + bvv;
      if (doRs) v *= rowscale[r0 + t];
      if (act) v = 0.5f * v * (1.f + tanhf(0.7978845608028654f * (v + 0.044715f * v * v * v)));
      if (addF) v += addF[cof + (ll)(r0 + t) * ldc + cn];
      vv[t] = v;
    }
    if (cn < splitcol) {
      if (outF) {
        #pragma unroll
        for (int t = 0; t < 4; ++t) outF[cof + (ll)(r0 + t) * ldc + cn] = vv[t];
      }
      if (outB) {
        #pragma unroll
        for (int t = 0; t < 4; ++t) outB[cof + (ll)(r0 + t) * ldc + cn] = f2bf(vv[t]);
      }
    } else {
      u16x4 pk = {f2bf(vv[0]), f2bf(vv[1]), f2bf(vv[2]), f2bf(vv[3])};
      *(u16x4*)(outBT + tof + (ll)(cn - splitcol) * ldt + r0) = pk;
    }
  }
}

// ---------------- consolidated weight prep: 16 transposes in ONE dispatch ----------------
struct PrepTable {
  const float* src[16];
  u16* dst[16];
  int R[16];
  int C[16];
  int off[17];
};

__global__ __launch_bounds__(256)
void k_prep_all(PrepTable T)
{
  __shared__ float t[32][33];
  const int b = blockIdx.x;
  int w = 0;
  #pragma unroll
  for (int i = 1; i < 16; ++i) if (b >= T.off[i]) w = i;
  const int lb = b - T.off[w];
  const int tilesC = T.C[w] >> 5;
  const int by = (lb / tilesC) << 5;
  const int bx = (lb - (lb / tilesC) * tilesC) << 5;
  const float* in = T.src[w];
  u16* out = T.dst[w];
  const int R = T.R[w], C = T.C[w];
  const int tx = threadIdx.x & 31, ty = threadIdx.x >> 5;
  #pragma unroll
  for (int i = 0; i < 32; i += 8)
    t[ty + i][tx] = in[(ll)(by + ty + i) * C + bx + tx];
  __syncthreads();
  #pragma unroll
  for (int i = 0; i < 32; i += 8)
    out[(ll)(bx + ty + i) * R + by + tx] = f2bf(t[tx][ty + i]);
}

__global__ __launch_bounds__(256)
void k_cvt(const float* __restrict__ in, u16* __restrict__ out, int n)
{
  int i = blockIdx.x * 256 + threadIdx.x;
  if (i < n) out[i] = f2bf(in[i]);
}

__global__ __launch_bounds__(256)
void k_cat3f(float* __restrict__ dst, const float* __restrict__ a, int na,
             const float* __restrict__ b, int nb, const float* __restrict__ c, int nc)
{
  int i = blockIdx.x * 256 + threadIdx.x;
  if (i < na) dst[i] = a[i];
  else if (i < na + nb) dst[i] = b[i - na];
  else if (i < na + nb + nc) dst[i] = c[i - na - nb];
}

// ---------------- row softmax on bf16 in place (cols <= 1024) ----------------
__global__ __launch_bounds__(256)
void k_softmax_b16(u16* __restrict__ x, int cols, float scale)
{
  u16* p = x + (ll)blockIdx.x * cols;
  const int tid = threadIdx.x;
  __shared__ float red[256];
  float v[4];
  float m = -1e30f;
  #pragma unroll
  for (int i = 0; i < 4; ++i) {
    const int c = tid + (i << 8);
    v[i] = (c < cols) ? bf2f(p[c]) * scale : -1e30f;
    m = fmaxf(m, v[i]);
  }
  red[tid] = m; __syncthreads();
  for (int s = 128; s > 0; s >>= 1) { if (tid < s) red[tid] = fmaxf(red[tid], red[tid + s]); __syncthreads(); }
  m = red[0]; __syncthreads();
  float sum = 0.f;
  #pragma unroll
  for (int i = 0; i < 4; ++i) { v[i] = expf(v[i] - m); sum += v[i]; }
  red[tid] = sum; __syncthreads();
  for (int s = 128; s > 0; s >>= 1) { if (tid < s) red[tid] += red[tid + s]; __syncthreads(); }
  const float inv = 1.f / red[0];
  #pragma unroll
  for (int i = 0; i < 4; ++i) {
    const int c = tid + (i << 8);
    if (c < cols) p[c] = f2bf(v[i] * inv);
  }
}

// ---------------- layernorm: LN(x [+res][+res2][+rbias])*g + b ----------------
__global__ __launch_bounds__(256)
void k_layernorm(const float* __restrict__ x, const float* __restrict__ res,
                 const float* __restrict__ res2, const float* __restrict__ rbias,
                 const float* __restrict__ g, const float* __restrict__ b,
                 float* __restrict__ outF, u16* __restrict__ outB, int cols)
{
  const ll ro = (ll)blockIdx.x * cols;
  const float* px = x + ro;
  const float* pr = res ? res + ro : nullptr;
  const float* p2 = res2 ? res2 + ro : nullptr;
  __shared__ float red[256];
  const int tid = threadIdx.x;
  auto val = [&](int c) {
    float v = px[c];
    if (pr) v += pr[c];
    if (p2) v += p2[c];
    if (rbias) v += rbias[c];
    return v;
  };
  float s = 0.f;
  for (int c = tid; c < cols; c += 256) s += val(c);
  red[tid] = s; __syncthreads();
  for (int t = 128; t > 0; t >>= 1) { if (tid < t) red[tid] += red[tid + t]; __syncthreads(); }
  const float mean = red[0] / cols; __syncthreads();
  float s2 = 0.f;
  for (int c = tid; c < cols; c += 256) { float v = val(c) - mean; s2 += v * v; }
  red[tid] = s2; __syncthreads();
  for (int t = 128; t > 0; t >>= 1) { if (tid < t) red[tid] += red[tid + t]; __syncthreads(); }
  const float inv = rsqrtf(red[0] / cols + 1e-5f);
  for (int c = tid; c < cols; c += 256) {
    float v = (val(c) - mean) * inv * g[c] + b[c];
    if (outF) outF[ro + c] = v;
    if (outB) outB[ro + c] = f2bf(v);
  }
}

// ---- fused: henh = h + sigmoid(h.rgw+b0)*r; bb = bf16(LN(henh)*g+b) ----
__global__ __launch_bounds__(256)
void k_gate_add_ln(const float* __restrict__ h, const float* __restrict__ rr,
                   const float* __restrict__ w, const float* __restrict__ b0,
                   const float* __restrict__ g, const float* __restrict__ b,
                   float* __restrict__ outF, u16* __restrict__ outB)
{
  constexpr int C = 1024;
  const ll ro = (ll)blockIdx.x * C;
  const float* ph = h + ro;
  const float* pr = rr + ro;
  __shared__ float red[256];
  const int tid = threadIdx.x;
  float hv[4], rv[4];
  float s = 0.f;
  #pragma unroll
  for (int i = 0; i < 4; ++i) {
    const int c = tid + (i << 8);
    hv[i] = ph[c]; rv[i] = pr[c];
    s += hv[i] * w[c];
  }
  red[tid] = s; __syncthreads();
  for (int t = 128; t > 0; t >>= 1) { if (tid < t) red[tid] += red[tid + t]; __syncthreads(); }
  const float gate = 1.0f / (1.0f + expf(-(red[0] + b0[0])));
  __syncthreads();
  float vsum = 0.f;
  float vv[4];
  #pragma unroll
  for (int i = 0; i < 4; ++i) { vv[i] = hv[i] + gate * rv[i]; vsum += vv[i]; }
  red[tid] = vsum; __syncthreads();
  for (int t = 128; t > 0; t >>= 1) { if (tid < t) red[tid] += red[tid + t]; __syncthreads(); }
  const float mean = red[0] / C; __syncthreads();
  float v2 = 0.f;
  #pragma unroll
  for (int i = 0; i < 4; ++i) { float d = vv[i] - mean; v2 += d * d; }
  red[tid] = v2; __syncthreads();
  for (int t = 128; t > 0; t >>= 1) { if (tid < t) red[tid] += red[tid + t]; __syncthreads(); }
  const float inv = rsqrtf(red[0] / C + 1e-5f);
  #pragma unroll
  for (int i = 0; i < 4; ++i) {
    const int c = tid + (i << 8);
    outF[ro + c] = vv[i];
    outB[ro + c] = f2bf((vv[i] - mean) * inv * g[c] + b[c]);
  }
}

__global__ __launch_bounds__(256)
void k_gate(const float* __restrict__ x, const float* __restrict__ w,
            const float* __restrict__ b0, float* __restrict__ out, int cols)
{
  const int lane = threadIdx.x & 63;
  const int wv = threadIdx.x >> 6;
  const ll row = (ll)blockIdx.x * 4 + wv;
  const float* p = x + row * cols;
  float s = 0.f;
  for (int c = lane; c < cols; c += 64) s += p[c] * w[c];
  #pragma unroll
  for (int off = 32; off > 0; off >>= 1) s += __shfl_down(s, off);
  if (lane == 0) out[row] = 1.0f / (1.0f + expf(-(s + b0[0])));
}

// ---------------- elementwise ----------------
__global__ __launch_bounds__(256)
void k_combine2(float* __restrict__ oF, u16* __restrict__ oB,
                const float* __restrict__ a, float sa, const float* __restrict__ b,
                const float* __restrict__ emb, int n, int Dm1)
{
  int i = blockIdx.x * 256 + threadIdx.x;
  if (i >= n) return;
  float v = sa * a[i];
  if (b) v += b[i];
  v += emb[i & Dm1];
  oF[i] = v; oB[i] = f2bf(v);
}

// ---------------- host ----------------
extern "C" void kernel_launch(void* const* d_in, const int* in_sizes, int n_in,
                              void* d_out, int out_size, void* d_ws, size_t ws_size,
                              hipStream_t stream)
{
  (void)in_sizes; (void)n_in; (void)out_size;
  const float* x        = (const float*)d_in[0];
  const float* cache0   = (const float*)d_in[1];
  const float* iter_emb = (const float*)d_in[2];
  const float* rq_w     = (const float*)d_in[3];
  const float* rg_w     = (const float*)d_in[4];
  const float* rg_b     = (const float*)d_in[5];
  const float* ck_w     = (const float*)d_in[6];
  const float* cv_w     = (const float*)d_in[7];
  const float* aq_w     = (const float*)d_in[8];
  const float* ak_w     = (const float*)d_in[9];
  const float* av_w     = (const float*)d_in[10];
  const float* ao_w     = (const float*)d_in[11];
  const float* aq_b     = (const float*)d_in[12];
  const float* ak_b     = (const float*)d_in[13];
  const float* av_b     = (const float*)d_in[14];
  const float* ao_b     = (const float*)d_in[15];
  const float* f1_w     = (const float*)d_in[16];
  const float* f1_b     = (const float*)d_in[17];
  const float* f2_w     = (const float*)d_in[18];
  const float* f2_b     = (const float*)d_in[19];
  const float* n1_g     = (const float*)d_in[20];
  const float* n1_b     = (const float*)d_in[21];
  const float* n2_g     = (const float*)d_in[22];
  const float* n2_b     = (const float*)d_in[23];
  const float* sq_w     = (const float*)d_in[24];
  const float* tk_w     = (const float*)d_in[25];
  const float* tv_w     = (const float*)d_in[26];
  const float* wg_w     = (const float*)d_in[27];
  const float* wg_b     = (const float*)d_in[28];
  const float* cq_w     = (const float*)d_in[29];
  const float* ck2_w    = (const float*)d_in[30];
  const float* cv2_w    = (const float*)d_in[31];
  const float* co_w     = (const float*)d_in[32];
  const float* cq_b     = (const float*)d_in[33];
  const float* ck2_b    = (const float*)d_in[34];
  const float* cv2_b    = (const float*)d_in[35];
  const float* co_b     = (const float*)d_in[36];
  const float* cn_g     = (const float*)d_in[37];
  const float* cn_b     = (const float*)d_in[38];
  // d_in[39] = max_iterations (fixed 2; schedule hardcoded for graph capture)

  float* out = (float*)d_out;

  // -------- workspace carve --------
  size_t off = 0;
  char* base = (char*)d_ws;
  auto allocF = [&](size_t n) { float* p = (float*)(base + off); off += n * 4; off = (off + 255) & ~(size_t)255; return p; };
  auto allocH = [&](size_t n) { u16* p = (u16*)(base + off); off += n * 2; off = (off + 255) & ~(size_t)255; return p; };

  float* hbuf  = allocF((size_t)BS_ * D_);
  float* henh  = allocF((size_t)BS_ * D_);
  float* hcomp = allocF((size_t)BS_ * D_);
  float* h2b   = allocF((size_t)BS_ * D_);
  float* tA    = allocF((size_t)2 * BS_ * D_);
  float* gate  = allocF((size_t)BS_);
  float* ccnf  = allocF((size_t)BNS_ * DS_);
  float* coo   = allocF((size_t)BNS_ * DS_);
  float* ccwf  = allocF((size_t)BNS_ * DS_);
  float* qkvb  = allocF(3 * D_);
  float* cqkvb = allocF(3 * DS_);
  u16* rqT  = allocH((size_t)D_ * D_);
  u16* ckT  = allocH((size_t)D_ * DS_);
  u16* cvT  = allocH((size_t)D_ * DS_);
  u16* aqT  = allocH((size_t)D_ * D_);
  u16* akT  = allocH((size_t)D_ * D_);
  u16* avT  = allocH((size_t)D_ * D_);
  u16* aoT  = allocH((size_t)D_ * D_);
  u16* f1T  = allocH((size_t)DFF_ * D_);
  u16* f2T  = allocH((size_t)D_ * DFF_);
  u16* sqT  = allocH((size_t)DS_ * DS_);
  u16* tkT  = allocH((size_t)DS_ * D_);
  u16* tvTw = allocH((size_t)DS_ * D_);
  u16* cqT  = allocH((size_t)DS_ * DS_);
  u16* ck2T = allocH((size_t)DS_ * DS_);
  u16* cv2T = allocH((size_t)DS_ * DS_);
  u16* coT  = allocH((size_t)DS_ * DS_);
  u16* bb1  = allocH((size_t)BS_ * D_);
  u16* bb2  = allocH((size_t)BS_ * D_);
  u16* bb3  = allocH((size_t)BS_ * D_);
  u16* bb4  = allocH((size_t)BS_ * D_);
  u16* bb5  = allocH((size_t)B_ * H_ * S_ * S_);
  u16* bbQK = allocH((size_t)BS_ * 2 * D_);
  u16* bbCQK= allocH((size_t)BNS_ * 2 * DS_);
  u16* cc0b = allocH((size_t)BNS_ * DS_);
  u16* ccwb = allocH((size_t)BNS_ * DS_);
  u16* sqb  = allocH((size_t)BNS_ * DS_);
  u16* tkb  = allocH((size_t)BS_ * DS_);
  u16* tvTb = allocH((size_t)DS_ * BS_);
  u16* ccnb = allocH((size_t)BNS_ * DS_);
  u16* cv2Tb= allocH((size_t)DS_ * BNS_);
  u16* csab = allocH((size_t)BNS_ * DS_);
  if (off > ws_size) return;
  (void)cvT; (void)akT; (void)avT; (void)tvTw; (void)ck2T; (void)cv2T;

  auto gemm = [&](int M, int N, int K, int z, int zdiv,
                  const u16* Ap, int lda, ll sa, ll sa2,
                  const u16* Bq, int ldb, ll sb, ll sb2,
                  float* oF, u16* oB, int ldc, ll sc, ll sc2,
                  u16* oBT, int ldt, ll st, ll st2,
                  const float* bias, const float* rsc, int rscfrom,
                  const float* addF, int splitcol, int act) {
    dim3 g(N / 64, M / 64, z);
    k_gemm<<<g, 256, 0, stream>>>(Ap, lda, sa, sa2, Bq, ldb, sb, sb2,
        oF, oB, ldc, sc, sc2, oBT, ldt, st, st2, K, zdiv, bias, rsc, rscfrom,
        addF, splitcol, act);
  };
  auto lnorm = [&](const float* xp, const float* rp, const float* rp2, const float* rb,
                   const float* g, const float* b, float* oF, u16* oB, int rows, int cols) {
    k_layernorm<<<rows, 256, 0, stream>>>(xp, rp, rp2, rb, g, b, oF, oB, cols);
  };
  auto eg = [](int n) { return dim3((n + 255) / 256); };

  // ---- weight prep: ONE dispatch for all 16 transposes ----
  {
    PrepTable T;
    const float* srcs[16] = {rq_w, ck_w, cv_w, aq_w, ak_w, av_w, ao_w, f1_w,
                             f2_w, sq_w, tk_w, tv_w, cq_w, ck2_w, cv2_w, co_w};
    u16* dsts[16] = {rqT, ckT, cvT, aqT, akT, avT, aoT, f1T,
                     f2T, sqT, tkT, tvTw, cqT, ck2T, cv2T, coT};
    const int Rs[16] = {D_, DS_, DS_, D_, D_, D_, D_, D_, DFF_, DS_, D_, D_, DS_, DS_, DS_, DS_};
    const int Cs[16] = {D_, D_, D_, D_, D_, D_, D_, DFF_, D_, DS_, DS_, DS_, DS_, DS_, DS_, DS_};
    int acc0 = 0;
    for (int i = 0; i < 16; ++i) {
      T.src[i] = srcs[i]; T.dst[i] = dsts[i]; T.R[i] = Rs[i]; T.C[i] = Cs[i];
      T.off[i] = acc0;
      acc0 += (Rs[i] >> 5) * (Cs[i] >> 5);
    }
    T.off[16] = acc0;
    k_prep_all<<<acc0, 256, 0, stream>>>(T);
  }
  k_cvt<<<eg(BNS_ * DS_), 256, 0, stream>>>(cache0, cc0b, BNS_ * DS_);
  k_cat3f<<<eg(3 * D_), 256, 0, stream>>>(qkvb, aq_b, D_, ak_b, D_, av_b, D_);
  k_cat3f<<<eg(3 * DS_), 256, 0, stream>>>(cqkvb, cq_b, DS_, ck2_b, DS_, cv2_b, DS_);

  // ---- mem_read: ends with fused gate+add+LN1 -> henh (fp32) + bb1 (bf16 LN) ----
  auto mem_read = [&](const float* h_f, const u16* h_b, const u16* cc_b, float* o_henh) {
    gemm(BS_, D_, D_, 1, 1, h_b, D_, 0, 0, rqT, D_, 0, 0,
         nullptr, bb2, D_, 0, 0, nullptr, 0, 0, 0,
         nullptr, nullptr, 0, nullptr, D_, 0);                                      // q
    gemm(BNS_, 2 * D_, DS_, 1, 1, cc_b, DS_, 0, 0, ckT, DS_, 0, 0,
         nullptr, bb3, D_, 0, 0, bb4, BNS_, 0, 0,
         nullptr, nullptr, 0, nullptr, D_, 0);                                      // k|v^T fused
    gemm(S_, NSLOT_, D_, B_, 1, bb2, D_, (ll)S_ * D_, 0,
         bb3, D_, (ll)NSLOT_ * D_, 0,
         nullptr, bb5, NSLOT_, (ll)S_ * NSLOT_, 0, nullptr, 0, 0, 0,
         nullptr, nullptr, 0, nullptr, NSLOT_, 0);                                  // q k^T
    k_softmax_b16<<<B_ * S_, 256, 0, stream>>>(bb5, NSLOT_, 0.03125f);
    gemm(S_, D_, NSLOT_, B_, 1, bb5, NSLOT_, (ll)S_ * NSLOT_, 0,
         bb4, BNS_, NSLOT_, 0,
         tA, nullptr, D_, (ll)S_ * D_, 0, nullptr, 0, 0, 0,
         nullptr, nullptr, 0, nullptr, D_, 0);                                      // readout
    k_gate_add_ln<<<BS_, 256, 0, stream>>>(h_f, tA, rg_w, rg_b, n1_g, n1_b,
                                           o_henh, bb1);                            // henh + LN1(bf16)
  };

  // ---- compute_block (bb1 = LN1(henh) already prepared by mem_read) ----
  auto compute_block = [&](const float* he, float* oF, u16* oB) {
    gemm(BS_, 3 * D_, D_, 1, 1, bb1, D_, 0, 0, aqT, D_, 0, 0,
         nullptr, bbQK, 2 * D_, 0, 0, bb4, BS_, 0, 0,
         qkvb, nullptr, 0, nullptr, 2 * D_, 0);                                     // qkv fused (va^T->bb4)
    gemm(S_, S_, HD_, B_ * H_, H_,
         bbQK, 2 * D_, (ll)S_ * 2 * D_, HD_,
         bbQK + D_, 2 * D_, (ll)S_ * 2 * D_, HD_,
         nullptr, bb5, S_, (ll)H_ * S_ * S_, (ll)S_ * S_, nullptr, 0, 0, 0,
         nullptr, nullptr, 0, nullptr, S_, 0);                                      // scores
    k_softmax_b16<<<B_ * H_ * S_, 256, 0, stream>>>(bb5, S_, 0.0625f);
    gemm(S_, HD_, S_, B_ * H_, H_,
         bb5, S_, (ll)H_ * S_ * S_, (ll)S_ * S_,
         bb4, BS_, S_, (ll)HD_ * BS_,
         nullptr, bb2, D_, (ll)S_ * D_, HD_, nullptr, 0, 0, 0,
         nullptr, nullptr, 0, nullptr, HD_, 0);                                     // attnv
    gemm(BS_, D_, D_, 1, 1, bb2, D_, 0, 0, aoT, D_, 0, 0,
         tA, nullptr, D_, 0, 0, nullptr, 0, 0, 0,
         ao_b, nullptr, 0, nullptr, D_, 0);                                         // attno
    lnorm(he, tA, nullptr, nullptr, n1_g, n1_b, h2b, bb1, BS_, D_);                 // h2
    gemm(BS_, DFF_, D_, 1, 1, bb1, D_, 0, 0, f1T, D_, 0, 0,
         nullptr, bb5, DFF_, 0, 0, nullptr, 0, 0, 0,
         f1_b, nullptr, 0, nullptr, DFF_, 1);                                       // f1+gelu
    gemm(BS_, D_, 2048, 2, 2, bb5, DFF_, 0, 2048, f2T, DFF_, 0, 2048,
         tA, nullptr, D_, 0, (ll)BS_ * D_, nullptr, 0, 0, 0,
         nullptr, nullptr, 0, nullptr, D_, 0);                                      // f2 split-K=2
    lnorm(h2b, tA, tA + (ll)BS_ * D_, f2_b, n2_g, n2_b, oF, oB, BS_, D_);           // LN(h2+p0+p1+f2_b)
  };

  // ---- mem_write + cache self-attn (skipped in last iter) ----
  auto mem_write_csa = [&](const float* hc_f, const u16* hc_b,
                           const float* ccin_f, const u16* ccin_b) {
    gemm(BNS_, DS_, DS_, 1, 1, ccin_b, DS_, 0, 0, sqT, DS_, 0, 0,
         nullptr, sqb, DS_, 0, 0, nullptr, 0, 0, 0,
         nullptr, nullptr, 0, nullptr, DS_, 0);                                     // sq
    k_gate<<<BS_ / 4, 256, 0, stream>>>(hc_f, wg_w, wg_b, gate, D_);
    gemm(BS_, 2 * DS_, D_, 1, 1, hc_b, D_, 0, 0, tkT, D_, 0, 0,
         nullptr, tkb, DS_, 0, 0, tvTb, BS_, 0, 0,
         nullptr, gate, DS_, nullptr, DS_, 0);                                      // tk | (gate*tv)^T
    gemm(NSLOT_, S_, DS_, B_, 1, sqb, DS_, (ll)NSLOT_ * DS_, 0,
         tkb, DS_, (ll)S_ * DS_, 0,
         nullptr, bb5, S_, (ll)NSLOT_ * S_, 0, nullptr, 0, 0, 0,
         nullptr, nullptr, 0, nullptr, S_, 0);                                      // slot scores
    k_softmax_b16<<<B_ * NSLOT_, 256, 0, stream>>>(bb5, S_, 0.05590169943749474f);
    gemm(NSLOT_, DS_, S_, B_, 1, bb5, S_, (ll)NSLOT_ * S_, 0,
         tvTb, BS_, S_, 0,
         ccnf, ccnb, DS_, (ll)NSLOT_ * DS_, 0, nullptr, 0, 0, 0,
         nullptr, nullptr, 0, ccin_f, DS_, 0);                                      // cc_new = ccin + upd (fused)
    gemm(BNS_, 3 * DS_, DS_, 1, 1, ccnb, DS_, 0, 0, cqT, DS_, 0, 0,
         nullptr, bbCQK, 2 * DS_, 0, 0, cv2Tb, BNS_, 0, 0,
         cqkvb, nullptr, 0, nullptr, 2 * DS_, 0);                                   // cq|ck|cv^T fused
    gemm(NSLOT_, NSLOT_, CHD_, B_ * CH_, CH_,
         bbCQK, 2 * DS_, (ll)NSLOT_ * 2 * DS_, CHD_,
         bbCQK + DS_, 2 * DS_, (ll)NSLOT_ * 2 * DS_, CHD_,
         nullptr, bb5, NSLOT_, (ll)CH_ * NSLOT_ * NSLOT_, (ll)NSLOT_ * NSLOT_,
         nullptr, 0, 0, 0, nullptr, nullptr, 0, nullptr, NSLOT_, 0);                // csa scores
    k_softmax_b16<<<B_ * CH_ * NSLOT_, 256, 0, stream>>>(bb5, NSLOT_, 0.125f);
    gemm(NSLOT_, CHD_, NSLOT_, B_ * CH_, CH_,
         bb5, NSLOT_, (ll)CH_ * NSLOT_ * NSLOT_, (ll)NSLOT_ * NSLOT_,
         cv2Tb, BNS_, NSLOT_, (ll)CHD_ * BNS_,
         nullptr, csab, DS_, (ll)NSLOT_ * DS_, CHD_, nullptr, 0, 0, 0,
         nullptr, nullptr, 0, nullptr, CHD_, 0);                                    // csa pv
    gemm(BNS_, DS_, DS_, 1, 1, csab, DS_, 0, 0, coT, DS_, 0, 0,
         coo, nullptr, DS_, 0, 0, nullptr, 0, 0, 0,
         co_b, nullptr, 0, nullptr, DS_, 0);                                        // co
    lnorm(ccnf, coo, nullptr, nullptr, cn_g, cn_b, ccwf, ccwb, BNS_, DS_);
  };

  // ================= iteration 0 =================
  k_combine2<<<eg(BS_ * D_), 256, 0, stream>>>(hbuf, bb1, x, 1.0f, nullptr, iter_emb, BS_ * D_, D_ - 1);
  mem_read(hbuf, bb1, cc0b, henh);
  compute_block(henh, hcomp, bb3);
  mem_write_csa(hcomp, bb3, cache0, cc0b);

  // ================= iteration 1 (last: cache update dead, skipped) =================
  k_combine2<<<eg(BS_ * D_), 256, 0, stream>>>(hbuf, bb1, hcomp, 2.0f, x, iter_emb + D_, BS_ * D_, D_ - 1);
  mem_read(hbuf, bb1, ccwb, henh);
  compute_block(henh, out, nullptr);
}

// Round 17
// 541.792 us; speedup vs baseline: 1.0386x; 1.0386x over previous
//
#include <hip/hip_runtime.h>
#include <cstdint>

// ---------------- problem constants ----------------
constexpr int B_ = 2, S_ = 1024, D_ = 1024, DS_ = 320, NSLOT_ = 512;
constexpr int H_ = 4, CH_ = 5, DFF_ = 4096;
constexpr int HD_ = D_ / H_;      // 256
constexpr int CHD_ = DS_ / CH_;   // 64
constexpr int BS_ = B_ * S_;      // 2048
constexpr int BNS_ = B_ * NSLOT_; // 1024

typedef unsigned short u16;
typedef __attribute__((ext_vector_type(8))) short bf16x8;
typedef __attribute__((ext_vector_type(4))) float f32x4;
typedef __attribute__((ext_vector_type(4))) u16 u16x4;
typedef long long ll;

__device__ __forceinline__ u16 f2bf(float f) {
  unsigned u = __float_as_uint(f);
  return (u16)((u + 0x7FFFu + ((u >> 16) & 1u)) >> 16);  // RNE
}
__device__ __forceinline__ float bf2f(u16 h) { return __uint_as_float((unsigned)h << 16); }

__device__ __forceinline__ void gload16(const void* g, void* l) {
  __builtin_amdgcn_global_load_lds((const __attribute__((address_space(1))) void*)g,
                                   (__attribute__((address_space(3))) void*)l, 16, 0, 0);
}

// ---------------- bf16 MFMA GEMM (r15 config — best measured, 530.9us total) ----------------
// BM=128, BN=64, BK=64, 512 thr (8 waves 8Mx1N, per-wave 16x64).
// TRIPLE-buffered LDS (3 x 24KB = 72KB -> 2 blocks/CU). Counted vmcnt:
// tile t+2 staged at step t; wait vmcnt(3) per step (t+1 stays in flight);
// vmcnt(0) only on final step. XOR-swizzled LDS (0 conflicts, verified).
// r17: + addF residual epilogue (fuses cc_new = cc_in + upd).
__global__ __launch_bounds__(512, 4)
void k_gemm(const u16* __restrict__ A, int lda, ll sA, ll sA2,
            const u16* __restrict__ Bp, int ldb, ll sB, ll sB2,
            float* __restrict__ outF, u16* __restrict__ outB,
            int ldc, ll sC, ll sC2,
            u16* __restrict__ outBT, int ldt, ll sT, ll sT2,
            int K, int zdiv, const float* __restrict__ bias,
            const float* __restrict__ rowscale, int rscfrom,
            const float* __restrict__ addF,
            int splitcol, int act)
{
  constexpr int ABYT = 128 * 128;   // 16 KB
  constexpr int BBYT = 64 * 128;    // 8 KB
  constexpr int BUF = ABYT + BBYT;  // 24 KB
  const int z = blockIdx.z, zb = z / zdiv, zr = z - zb * zdiv;
  A  += (ll)zb * sA + (ll)zr * sA2;
  Bp += (ll)zb * sB + (ll)zr * sB2;
  const ll cof = (ll)zb * sC + (ll)zr * sC2;
  const ll tof = (ll)zb * sT + (ll)zr * sT2;
  const int bm = blockIdx.y * 128, bn = blockIdx.x * 64;
  __shared__ __align__(16) char lds[3 * BUF];   // 72 KB
  const int tid = threadIdx.x;
  const int lane = tid & 63, wid = tid >> 6;
  const int rowb = wid * 16;                    // 8 waves x 16 rows

  f32x4 acc[4];
  const f32x4 fz = {0.f, 0.f, 0.f, 0.f};
  #pragma unroll
  for (int j = 0; j < 4; ++j) acc[j] = fz;

  const int trow = tid >> 3;
  const int tg   = ((tid & 7) ^ (trow & 7)) * 8;
  const u16* gA  = A + (ll)(bm + trow) * lda + tg;
  const u16* gA2 = gA + (ll)64 * lda;
  const u16* gB  = Bp + (ll)(bn + trow) * ldb + tg;

  const int r = lane & 15, q = lane >> 4;
  const int c7 = r & 7;
  const int gs0 = ((q) ^ c7) << 4;
  const int gs1 = ((4 + q) ^ c7) << 4;
  const int aoff = (rowb + r) * 128;
  int boff[4];
  #pragma unroll
  for (int j = 0; j < 4; ++j) boff[j] = ABYT + (j * 16 + r) * 128;

  auto stage = [&](int buf, int it) {
    char* la = lds + buf * BUF + wid * 1024;
    char* lb = la + ABYT;
    const int ko = it << 6;
    gload16(gA + ko, la);
    gload16(gA2 + ko, la + 8192);
    gload16(gB + ko, lb);
  };

  const int nsteps = K >> 6;
  stage(0, 0);
  if (nsteps > 1) stage(1, 1);
  for (int it = 0; it < nsteps; ++it) {
    if (it == nsteps - 1) asm volatile("s_waitcnt vmcnt(0)" ::: "memory");
    else                  asm volatile("s_waitcnt vmcnt(3)" ::: "memory");
    __builtin_amdgcn_s_barrier();            // all waves' tile-t loads landed
    __builtin_amdgcn_sched_barrier(0);
    if (it + 2 < nsteps) {
      int nb = it + 2; while (nb >= 3) nb -= 3;
      stage(nb, it + 2);                     // WAR-safe: readers passed barrier
    }
    int p = it; while (p >= 3) p -= 3;
    const char* pa = lds + p * BUF;
    #pragma unroll
    for (int s = 0; s < 2; ++s) {
      const int gso = s ? gs1 : gs0;
      bf16x8 af = *(const bf16x8*)(pa + aoff + gso);
      bf16x8 bv[4];
      #pragma unroll
      for (int j = 0; j < 4; ++j) bv[j] = *(const bf16x8*)(pa + boff[j] + gso);
      #pragma unroll
      for (int j = 0; j < 4; ++j)
        acc[j] = __builtin_amdgcn_mfma_f32_16x16x32_bf16(af, bv[j], acc[j], 0, 0, 0);
    }
    asm volatile("s_waitcnt lgkmcnt(0)" ::: "memory");  // reads of buf[p] done
    __builtin_amdgcn_sched_barrier(0);
  }

  const int fr = lane & 15, fq = lane >> 4;
  const int r0 = bm + rowb + fq * 4;
  #pragma unroll
  for (int j = 0; j < 4; ++j) {
    const int cn = bn + j * 16 + fr;
    const float bvv = bias ? bias[cn] : 0.f;
    const bool doRs = rowscale && (cn >= rscfrom);
    float vv[4];
    #pragma unroll
    for (int t = 0; t < 4; ++t) {
      float v = acc[j][t] + bvv;
      if (doRs) v *= rowscale[r0 + t];
      if (act) v = 0.5f * v * (1.f + tanhf(0.7978845608028654f * (v + 0.044715f * v * v * v)));
      if (addF) v += addF[cof + (ll)(r0 + t) * ldc + cn];
      vv[t] = v;
    }
    if (cn < splitcol) {
      if (outF) {
        #pragma unroll
        for (int t = 0; t < 4; ++t) outF[cof + (ll)(r0 + t) * ldc + cn] = vv[t];
      }
      if (outB) {
        #pragma unroll
        for (int t = 0; t < 4; ++t) outB[cof + (ll)(r0 + t) * ldc + cn] = f2bf(vv[t]);
      }
    } else {
      u16x4 pk = {f2bf(vv[0]), f2bf(vv[1]), f2bf(vv[2]), f2bf(vv[3])};
      *(u16x4*)(outBT + tof + (ll)(cn - splitcol) * ldt + r0) = pk;
    }
  }
}

// ---------------- consolidated weight prep: 16 transposes in ONE dispatch ----------------
struct PrepTable {
  const float* src[16];
  u16* dst[16];
  int R[16];
  int C[16];
  int off[17];
};

__global__ __launch_bounds__(256)
void k_prep_all(PrepTable T)
{
  __shared__ float t[32][33];
  const int b = blockIdx.x;
  int w = 0;
  #pragma unroll
  for (int i = 1; i < 16; ++i) if (b >= T.off[i]) w = i;
  const int lb = b - T.off[w];
  const int tilesC = T.C[w] >> 5;
  const int by = (lb / tilesC) << 5;
  const int bx = (lb - (lb / tilesC) * tilesC) << 5;
  const float* in = T.src[w];
  u16* out = T.dst[w];
  const int R = T.R[w], C = T.C[w];
  const int tx = threadIdx.x & 31, ty = threadIdx.x >> 5;
  #pragma unroll
  for (int i = 0; i < 32; i += 8)
    t[ty + i][tx] = in[(ll)(by + ty + i) * C + bx + tx];
  __syncthreads();
  #pragma unroll
  for (int i = 0; i < 32; i += 8)
    out[(ll)(bx + ty + i) * R + by + tx] = f2bf(t[tx][ty + i]);
}

__global__ __launch_bounds__(256)
void k_cvt(const float* __restrict__ in, u16* __restrict__ out, int n)
{
  int i = blockIdx.x * 256 + threadIdx.x;
  if (i < n) out[i] = f2bf(in[i]);
}

__global__ __launch_bounds__(256)
void k_cat3f(float* __restrict__ dst, const float* __restrict__ a, int na,
             const float* __restrict__ b, int nb, const float* __restrict__ c, int nc)
{
  int i = blockIdx.x * 256 + threadIdx.x;
  if (i < na) dst[i] = a[i];
  else if (i < na + nb) dst[i] = b[i - na];
  else if (i < na + nb + nc) dst[i] = c[i - na - nb];
}

// ---------------- row softmax on bf16 in place (cols <= 1024) ----------------
__global__ __launch_bounds__(256)
void k_softmax_b16(u16* __restrict__ x, int cols, float scale)
{
  u16* p = x + (ll)blockIdx.x * cols;
  const int tid = threadIdx.x;
  __shared__ float red[256];
  float v[4];
  float m = -1e30f;
  #pragma unroll
  for (int i = 0; i < 4; ++i) {
    const int c = tid + (i << 8);
    v[i] = (c < cols) ? bf2f(p[c]) * scale : -1e30f;
    m = fmaxf(m, v[i]);
  }
  red[tid] = m; __syncthreads();
  for (int s = 128; s > 0; s >>= 1) { if (tid < s) red[tid] = fmaxf(red[tid], red[tid + s]); __syncthreads(); }
  m = red[0]; __syncthreads();
  float sum = 0.f;
  #pragma unroll
  for (int i = 0; i < 4; ++i) { v[i] = expf(v[i] - m); sum += v[i]; }
  red[tid] = sum; __syncthreads();
  for (int s = 128; s > 0; s >>= 1) { if (tid < s) red[tid] += red[tid + s]; __syncthreads(); }
  const float inv = 1.f / red[0];
  #pragma unroll
  for (int i = 0; i < 4; ++i) {
    const int c = tid + (i << 8);
    if (c < cols) p[c] = f2bf(v[i] * inv);
  }
}

// ---------------- layernorm: LN(x [+res][+res2][+rbias])*g + b ----------------
__global__ __launch_bounds__(256)
void k_layernorm(const float* __restrict__ x, const float* __restrict__ res,
                 const float* __restrict__ res2, const float* __restrict__ rbias,
                 const float* __restrict__ g, const float* __restrict__ b,
                 float* __restrict__ outF, u16* __restrict__ outB, int cols)
{
  const ll ro = (ll)blockIdx.x * cols;
  const float* px = x + ro;
  const float* pr = res ? res + ro : nullptr;
  const float* p2 = res2 ? res2 + ro : nullptr;
  __shared__ float red[256];
  const int tid = threadIdx.x;
  auto val = [&](int c) {
    float v = px[c];
    if (pr) v += pr[c];
    if (p2) v += p2[c];
    if (rbias) v += rbias[c];
    return v;
  };
  float s = 0.f;
  for (int c = tid; c < cols; c += 256) s += val(c);
  red[tid] = s; __syncthreads();
  for (int t = 128; t > 0; t >>= 1) { if (tid < t) red[tid] += red[tid + t]; __syncthreads(); }
  const float mean = red[0] / cols; __syncthreads();
  float s2 = 0.f;
  for (int c = tid; c < cols; c += 256) { float v = val(c) - mean; s2 += v * v; }
  red[tid] = s2; __syncthreads();
  for (int t = 128; t > 0; t >>= 1) { if (tid < t) red[tid] += red[tid + t]; __syncthreads(); }
  const float inv = rsqrtf(red[0] / cols + 1e-5f);
  for (int c = tid; c < cols; c += 256) {
    float v = (val(c) - mean) * inv * g[c] + b[c];
    if (outF) outF[ro + c] = v;
    if (outB) outB[ro + c] = f2bf(v);
  }
}

// ---- fused: henh = h + sigmoid(h.rgw+b0)*r; bb = bf16(LN(henh)*g+b) ----
__global__ __launch_bounds__(256)
void k_gate_add_ln(const float* __restrict__ h, const float* __restrict__ rr,
                   const float* __restrict__ w, const float* __restrict__ b0,
                   const float* __restrict__ g, const float* __restrict__ b,
                   float* __restrict__ outF, u16* __restrict__ outB)
{
  constexpr int C = 1024;
  const ll ro = (ll)blockIdx.x * C;
  const float* ph = h + ro;
  const float* pr = rr + ro;
  __shared__ float red[256];
  const int tid = threadIdx.x;
  float hv[4], rv[4];
  float s = 0.f;
  #pragma unroll
  for (int i = 0; i < 4; ++i) {
    const int c = tid + (i << 8);
    hv[i] = ph[c]; rv[i] = pr[c];
    s += hv[i] * w[c];
  }
  red[tid] = s; __syncthreads();
  for (int t = 128; t > 0; t >>= 1) { if (tid < t) red[tid] += red[tid + t]; __syncthreads(); }
  const float gate = 1.0f / (1.0f + expf(-(red[0] + b0[0])));
  __syncthreads();
  float vsum = 0.f;
  float vv[4];
  #pragma unroll
  for (int i = 0; i < 4; ++i) { vv[i] = hv[i] + gate * rv[i]; vsum += vv[i]; }
  red[tid] = vsum; __syncthreads();
  for (int t = 128; t > 0; t >>= 1) { if (tid < t) red[tid] += red[tid + t]; __syncthreads(); }
  const float mean = red[0] / C; __syncthreads();
  float v2 = 0.f;
  #pragma unroll
  for (int i = 0; i < 4; ++i) { float d = vv[i] - mean; v2 += d * d; }
  red[tid] = v2; __syncthreads();
  for (int t = 128; t > 0; t >>= 1) { if (tid < t) red[tid] += red[tid + t]; __syncthreads(); }
  const float inv = rsqrtf(red[0] / C + 1e-5f);
  #pragma unroll
  for (int i = 0; i < 4; ++i) {
    const int c = tid + (i << 8);
    outF[ro + c] = vv[i];
    outB[ro + c] = f2bf((vv[i] - mean) * inv * g[c] + b[c]);
  }
}

__global__ __launch_bounds__(256)
void k_gate(const float* __restrict__ x, const float* __restrict__ w,
            const float* __restrict__ b0, float* __restrict__ out, int cols)
{
  const int lane = threadIdx.x & 63;
  const int wv = threadIdx.x >> 6;
  const ll row = (ll)blockIdx.x * 4 + wv;
  const float* p = x + row * cols;
  float s = 0.f;
  for (int c = lane; c < cols; c += 64) s += p[c] * w[c];
  #pragma unroll
  for (int off = 32; off > 0; off >>= 1) s += __shfl_down(s, off);
  if (lane == 0) out[row] = 1.0f / (1.0f + expf(-(s + b0[0])));
}

// ---------------- elementwise ----------------
__global__ __launch_bounds__(256)
void k_combine2(float* __restrict__ oF, u16* __restrict__ oB,
                const float* __restrict__ a, float sa, const float* __restrict__ b,
                const float* __restrict__ emb, int n, int Dm1)
{
  int i = blockIdx.x * 256 + threadIdx.x;
  if (i >= n) return;
  float v = sa * a[i];
  if (b) v += b[i];
  v += emb[i & Dm1];
  oF[i] = v; oB[i] = f2bf(v);
}

// ---------------- host ----------------
extern "C" void kernel_launch(void* const* d_in, const int* in_sizes, int n_in,
                              void* d_out, int out_size, void* d_ws, size_t ws_size,
                              hipStream_t stream)
{
  (void)in_sizes; (void)n_in; (void)out_size;
  const float* x        = (const float*)d_in[0];
  const float* cache0   = (const float*)d_in[1];
  const float* iter_emb = (const float*)d_in[2];
  const float* rq_w     = (const float*)d_in[3];
  const float* rg_w     = (const float*)d_in[4];
  const float* rg_b     = (const float*)d_in[5];
  const float* ck_w     = (const float*)d_in[6];
  const float* cv_w     = (const float*)d_in[7];
  const float* aq_w     = (const float*)d_in[8];
  const float* ak_w     = (const float*)d_in[9];
  const float* av_w     = (const float*)d_in[10];
  const float* ao_w     = (const float*)d_in[11];
  const float* aq_b     = (const float*)d_in[12];
  const float* ak_b     = (const float*)d_in[13];
  const float* av_b     = (const float*)d_in[14];
  const float* ao_b     = (const float*)d_in[15];
  const float* f1_w     = (const float*)d_in[16];
  const float* f1_b     = (const float*)d_in[17];
  const float* f2_w     = (const float*)d_in[18];
  const float* f2_b     = (const float*)d_in[19];
  const float* n1_g     = (const float*)d_in[20];
  const float* n1_b     = (const float*)d_in[21];
  const float* n2_g     = (const float*)d_in[22];
  const float* n2_b     = (const float*)d_in[23];
  const float* sq_w     = (const float*)d_in[24];
  const float* tk_w     = (const float*)d_in[25];
  const float* tv_w     = (const float*)d_in[26];
  const float* wg_w     = (const float*)d_in[27];
  const float* wg_b     = (const float*)d_in[28];
  const float* cq_w     = (const float*)d_in[29];
  const float* ck2_w    = (const float*)d_in[30];
  const float* cv2_w    = (const float*)d_in[31];
  const float* co_w     = (const float*)d_in[32];
  const float* cq_b     = (const float*)d_in[33];
  const float* ck2_b    = (const float*)d_in[34];
  const float* cv2_b    = (const float*)d_in[35];
  const float* co_b     = (const float*)d_in[36];
  const float* cn_g     = (const float*)d_in[37];
  const float* cn_b     = (const float*)d_in[38];
  // d_in[39] = max_iterations (fixed 2; schedule hardcoded for graph capture)

  float* out = (float*)d_out;

  // -------- workspace carve --------
  size_t off = 0;
  char* base = (char*)d_ws;
  auto allocF = [&](size_t n) { float* p = (float*)(base + off); off += n * 4; off = (off + 255) & ~(size_t)255; return p; };
  auto allocH = [&](size_t n) { u16* p = (u16*)(base + off); off += n * 2; off = (off + 255) & ~(size_t)255; return p; };

  float* hbuf  = allocF((size_t)BS_ * D_);
  float* henh  = allocF((size_t)BS_ * D_);
  float* hcomp = allocF((size_t)BS_ * D_);
  float* h2b   = allocF((size_t)BS_ * D_);
  float* tA    = allocF((size_t)2 * BS_ * D_);
  float* gate  = allocF((size_t)BS_);
  float* ccnf  = allocF((size_t)BNS_ * DS_);
  float* coo   = allocF((size_t)BNS_ * DS_);
  float* ccwf  = allocF((size_t)BNS_ * DS_);
  float* qkvb  = allocF(3 * D_);
  float* cqkvb = allocF(3 * DS_);
  u16* rqT  = allocH((size_t)D_ * D_);
  u16* ckT  = allocH((size_t)D_ * DS_);
  u16* cvT  = allocH((size_t)D_ * DS_);
  u16* aqT  = allocH((size_t)D_ * D_);
  u16* akT  = allocH((size_t)D_ * D_);
  u16* avT  = allocH((size_t)D_ * D_);
  u16* aoT  = allocH((size_t)D_ * D_);
  u16* f1T  = allocH((size_t)DFF_ * D_);
  u16* f2T  = allocH((size_t)D_ * DFF_);
  u16* sqT  = allocH((size_t)DS_ * DS_);
  u16* tkT  = allocH((size_t)DS_ * D_);
  u16* tvTw = allocH((size_t)DS_ * D_);
  u16* cqT  = allocH((size_t)DS_ * DS_);
  u16* ck2T = allocH((size_t)DS_ * DS_);
  u16* cv2T = allocH((size_t)DS_ * DS_);
  u16* coT  = allocH((size_t)DS_ * DS_);
  u16* bb1  = allocH((size_t)BS_ * D_);
  u16* bb2  = allocH((size_t)BS_ * D_);
  u16* bb3  = allocH((size_t)BS_ * D_);
  u16* bb4  = allocH((size_t)BS_ * D_);
  u16* bb5  = allocH((size_t)B_ * H_ * S_ * S_);
  u16* bbQK = allocH((size_t)BS_ * 2 * D_);
  u16* bbCQK= allocH((size_t)BNS_ * 2 * DS_);
  u16* cc0b = allocH((size_t)BNS_ * DS_);
  u16* ccwb = allocH((size_t)BNS_ * DS_);
  u16* sqb  = allocH((size_t)BNS_ * DS_);
  u16* tkb  = allocH((size_t)BS_ * DS_);
  u16* tvTb = allocH((size_t)DS_ * BS_);
  u16* ccnb = allocH((size_t)BNS_ * DS_);
  u16* cv2Tb= allocH((size_t)DS_ * BNS_);
  u16* csab = allocH((size_t)BNS_ * DS_);
  if (off > ws_size) return;
  (void)cvT; (void)akT; (void)avT; (void)tvTw; (void)ck2T; (void)cv2T;

  auto gemm = [&](int M, int N, int K, int z, int zdiv,
                  const u16* Ap, int lda, ll sa, ll sa2,
                  const u16* Bq, int ldb, ll sb, ll sb2,
                  float* oF, u16* oB, int ldc, ll sc, ll sc2,
                  u16* oBT, int ldt, ll st, ll st2,
                  const float* bias, const float* rsc, int rscfrom,
                  const float* addF, int splitcol, int act) {
    dim3 g(N / 64, M / 128, z);
    k_gemm<<<g, 512, 0, stream>>>(Ap, lda, sa, sa2, Bq, ldb, sb, sb2,
        oF, oB, ldc, sc, sc2, oBT, ldt, st, st2, K, zdiv, bias, rsc, rscfrom,
        addF, splitcol, act);
  };
  auto lnorm = [&](const float* xp, const float* rp, const float* rp2, const float* rb,
                   const float* g, const float* b, float* oF, u16* oB, int rows, int cols) {
    k_layernorm<<<rows, 256, 0, stream>>>(xp, rp, rp2, rb, g, b, oF, oB, cols);
  };
  auto eg = [](int n) { return dim3((n + 255) / 256); };

  // ---- weight prep: ONE dispatch for all 16 transposes ----
  {
    PrepTable T;
    const float* srcs[16] = {rq_w, ck_w, cv_w, aq_w, ak_w, av_w, ao_w, f1_w,
                             f2_w, sq_w, tk_w, tv_w, cq_w, ck2_w, cv2_w, co_w};
    u16* dsts[16] = {rqT, ckT, cvT, aqT, akT, avT, aoT, f1T,
                     f2T, sqT, tkT, tvTw, cqT, ck2T, cv2T, coT};
    const int Rs[16] = {D_, DS_, DS_, D_, D_, D_, D_, D_, DFF_, DS_, D_, D_, DS_, DS_, DS_, DS_};
    const int Cs[16] = {D_, D_, D_, D_, D_, D_, D_, DFF_, D_, DS_, DS_, DS_, DS_, DS_, DS_, DS_};
    int acc0 = 0;
    for (int i = 0; i < 16; ++i) {
      T.src[i] = srcs[i]; T.dst[i] = dsts[i]; T.R[i] = Rs[i]; T.C[i] = Cs[i];
      T.off[i] = acc0;
      acc0 += (Rs[i] >> 5) * (Cs[i] >> 5);
    }
    T.off[16] = acc0;
    k_prep_all<<<acc0, 256, 0, stream>>>(T);
  }
  k_cvt<<<eg(BNS_ * DS_), 256, 0, stream>>>(cache0, cc0b, BNS_ * DS_);
  k_cat3f<<<eg(3 * D_), 256, 0, stream>>>(qkvb, aq_b, D_, ak_b, D_, av_b, D_);
  k_cat3f<<<eg(3 * DS_), 256, 0, stream>>>(cqkvb, cq_b, DS_, ck2_b, DS_, cv2_b, DS_);

  // ---- mem_read: ends with fused gate+add+LN1 -> henh (fp32) + bb1 (bf16 LN) ----
  auto mem_read = [&](const float* h_f, const u16* h_b, const u16* cc_b, float* o_henh) {
    gemm(BS_, D_, D_, 1, 1, h_b, D_, 0, 0, rqT, D_, 0, 0,
         nullptr, bb2, D_, 0, 0, nullptr, 0, 0, 0,
         nullptr, nullptr, 0, nullptr, D_, 0);                                      // q
    gemm(BNS_, 2 * D_, DS_, 1, 1, cc_b, DS_, 0, 0, ckT, DS_, 0, 0,
         nullptr, bb3, D_, 0, 0, bb4, BNS_, 0, 0,
         nullptr, nullptr, 0, nullptr, D_, 0);                                      // k|v^T fused
    gemm(S_, NSLOT_, D_, B_, 1, bb2, D_, (ll)S_ * D_, 0,
         bb3, D_, (ll)NSLOT_ * D_, 0,
         nullptr, bb5, NSLOT_, (ll)S_ * NSLOT_, 0, nullptr, 0, 0, 0,
         nullptr, nullptr, 0, nullptr, NSLOT_, 0);                                  // q k^T
    k_softmax_b16<<<B_ * S_, 256, 0, stream>>>(bb5, NSLOT_, 0.03125f);
    gemm(S_, D_, NSLOT_, B_, 1, bb5, NSLOT_, (ll)S_ * NSLOT_, 0,
         bb4, BNS_, NSLOT_, 0,
         tA, nullptr, D_, (ll)S_ * D_, 0, nullptr, 0, 0, 0,
         nullptr, nullptr, 0, nullptr, D_, 0);                                      // readout
    k_gate_add_ln<<<BS_, 256, 0, stream>>>(h_f, tA, rg_w, rg_b, n1_g, n1_b,
                                           o_henh, bb1);                            // henh + LN1(bf16)
  };

  // ---- compute_block (bb1 = LN1(henh) already prepared by mem_read) ----
  auto compute_block = [&](const float* he, float* oF, u16* oB) {
    gemm(BS_, 3 * D_, D_, 1, 1, bb1, D_, 0, 0, aqT, D_, 0, 0,
         nullptr, bbQK, 2 * D_, 0, 0, bb4, BS_, 0, 0,
         qkvb, nullptr, 0, nullptr, 2 * D_, 0);                                     // qkv fused (va^T->bb4)
    gemm(S_, S_, HD_, B_ * H_, H_,
         bbQK, 2 * D_, (ll)S_ * 2 * D_, HD_,
         bbQK + D_, 2 * D_, (ll)S_ * 2 * D_, HD_,
         nullptr, bb5, S_, (ll)H_ * S_ * S_, (ll)S_ * S_, nullptr, 0, 0, 0,
         nullptr, nullptr, 0, nullptr, S_, 0);                                      // scores
    k_softmax_b16<<<B_ * H_ * S_, 256, 0, stream>>>(bb5, S_, 0.0625f);
    gemm(S_, HD_, S_, B_ * H_, H_,
         bb5, S_, (ll)H_ * S_ * S_, (ll)S_ * S_,
         bb4, BS_, S_, (ll)HD_ * BS_,
         nullptr, bb2, D_, (ll)S_ * D_, HD_, nullptr, 0, 0, 0,
         nullptr, nullptr, 0, nullptr, HD_, 0);                                     // attnv
    gemm(BS_, D_, D_, 1, 1, bb2, D_, 0, 0, aoT, D_, 0, 0,
         tA, nullptr, D_, 0, 0, nullptr, 0, 0, 0,
         ao_b, nullptr, 0, nullptr, D_, 0);                                         // attno
    lnorm(he, tA, nullptr, nullptr, n1_g, n1_b, h2b, bb1, BS_, D_);                 // h2
    gemm(BS_, DFF_, D_, 1, 1, bb1, D_, 0, 0, f1T, D_, 0, 0,
         nullptr, bb5, DFF_, 0, 0, nullptr, 0, 0, 0,
         f1_b, nullptr, 0, nullptr, DFF_, 1);                                       // f1+gelu
    gemm(BS_, D_, 2048, 2, 2, bb5, DFF_, 0, 2048, f2T, DFF_, 0, 2048,
         tA, nullptr, D_, 0, (ll)BS_ * D_, nullptr, 0, 0, 0,
         nullptr, nullptr, 0, nullptr, D_, 0);                                      // f2 split-K=2
    lnorm(h2b, tA, tA + (ll)BS_ * D_, f2_b, n2_g, n2_b, oF, oB, BS_, D_);           // LN(h2+p0+p1+f2_b)
  };

  // ---- mem_write + cache self-attn (skipped in last iter) ----
  auto mem_write_csa = [&](const float* hc_f, const u16* hc_b,
                           const float* ccin_f, const u16* ccin_b) {
    gemm(BNS_, DS_, DS_, 1, 1, ccin_b, DS_, 0, 0, sqT, DS_, 0, 0,
         nullptr, sqb, DS_, 0, 0, nullptr, 0, 0, 0,
         nullptr, nullptr, 0, nullptr, DS_, 0);                                     // sq
    k_gate<<<BS_ / 4, 256, 0, stream>>>(hc_f, wg_w, wg_b, gate, D_);
    gemm(BS_, 2 * DS_, D_, 1, 1, hc_b, D_, 0, 0, tkT, D_, 0, 0,
         nullptr, tkb, DS_, 0, 0, tvTb, BS_, 0, 0,
         nullptr, gate, DS_, nullptr, DS_, 0);                                      // tk | (gate*tv)^T
    gemm(NSLOT_, S_, DS_, B_, 1, sqb, DS_, (ll)NSLOT_ * DS_, 0,
         tkb, DS_, (ll)S_ * DS_, 0,
         nullptr, bb5, S_, (ll)NSLOT_ * S_, 0, nullptr, 0, 0, 0,
         nullptr, nullptr, 0, nullptr, S_, 0);                                      // slot scores
    k_softmax_b16<<<B_ * NSLOT_, 256, 0, stream>>>(bb5, S_, 0.05590169943749474f);
    gemm(NSLOT_, DS_, S_, B_, 1, bb5, S_, (ll)NSLOT_ * S_, 0,
         tvTb, BS_, S_, 0,
         ccnf, ccnb, DS_, (ll)NSLOT_ * DS_, 0, nullptr, 0, 0, 0,
         nullptr, nullptr, 0, ccin_f, DS_, 0);                                      // cc_new = ccin + upd (fused)
    gemm(BNS_, 3 * DS_, DS_, 1, 1, ccnb, DS_, 0, 0, cqT, DS_, 0, 0,
         nullptr, bbCQK, 2 * DS_, 0, 0, cv2Tb, BNS_, 0, 0,
         cqkvb, nullptr, 0, nullptr, 2 * DS_, 0);                                   // cq|ck|cv^T fused
    gemm(NSLOT_, NSLOT_, CHD_, B_ * CH_, CH_,
         bbCQK, 2 * DS_, (ll)NSLOT_ * 2 * DS_, CHD_,
         bbCQK + DS_, 2 * DS_, (ll)NSLOT_ * 2 * DS_, CHD_,
         nullptr, bb5, NSLOT_, (ll)CH_ * NSLOT_ * NSLOT_, (ll)NSLOT_ * NSLOT_,
         nullptr, 0, 0, 0, nullptr, nullptr, 0, nullptr, NSLOT_, 0);                // csa scores
    k_softmax_b16<<<B_ * CH_ * NSLOT_, 256, 0, stream>>>(bb5, NSLOT_, 0.125f);
    gemm(NSLOT_, CHD_, NSLOT_, B_ * CH_, CH_,
         bb5, NSLOT_, (ll)CH_ * NSLOT_ * NSLOT_, (ll)NSLOT_ * NSLOT_,
         cv2Tb, BNS_, NSLOT_, (ll)CHD_ * BNS_,
         nullptr, csab, DS_, (ll)NSLOT_ * DS_, CHD_, nullptr, 0, 0, 0,
         nullptr, nullptr, 0, nullptr, CHD_, 0);                                    // csa pv
    gemm(BNS_, DS_, DS_, 1, 1, csab, DS_, 0, 0, coT, DS_, 0, 0,
         coo, nullptr, DS_, 0, 0, nullptr, 0, 0, 0,
         co_b, nullptr, 0, nullptr, DS_, 0);                                        // co
    lnorm(ccnf, coo, nullptr, nullptr, cn_g, cn_b, ccwf, ccwb, BNS_, DS_);
  };

  // ================= iteration 0 =================
  k_combine2<<<eg(BS_ * D_), 256, 0, stream>>>(hbuf, bb1, x, 1.0f, nullptr, iter_emb, BS_ * D_, D_ - 1);
  mem_read(hbuf, bb1, cc0b, henh);
  compute_block(henh, hcomp, bb3);
  mem_write_csa(hcomp, bb3, cache0, cc0b);

  // ================= iteration 1 (last: cache update dead, skipped) =================
  k_combine2<<<eg(BS_ * D_), 256, 0, stream>>>(hbuf, bb1, hcomp, 2.0f, x, iter_emb + D_, BS_ * D_, D_ - 1);
  mem_read(hbuf, bb1, ccwb, henh);
  compute_block(henh, out, nullptr);
}

// Round 18
// 529.119 us; speedup vs baseline: 1.0634x; 1.0240x over previous
//
#include <hip/hip_runtime.h>
#include <cstdint>

// ---------------- problem constants ----------------
constexpr int B_ = 2, S_ = 1024, D_ = 1024, DS_ = 320, NSLOT_ = 512;
constexpr int H_ = 4, CH_ = 5, DFF_ = 4096;
constexpr int HD_ = D_ / H_;      // 256
constexpr int CHD_ = DS_ / CH_;   // 64
constexpr int BS_ = B_ * S_;      // 2048
constexpr int BNS_ = B_ * NSLOT_; // 1024

typedef unsigned short u16;
typedef __attribute__((ext_vector_type(8))) short bf16x8;
typedef __attribute__((ext_vector_type(4))) float f32x4;
typedef __attribute__((ext_vector_type(4))) u16 u16x4;
typedef long long ll;

__device__ __forceinline__ u16 f2bf(float f) {
  unsigned u = __float_as_uint(f);
  return (u16)((u + 0x7FFFu + ((u >> 16) & 1u)) >> 16);  // RNE
}
__device__ __forceinline__ float bf2f(u16 h) { return __uint_as_float((unsigned)h << 16); }

__device__ __forceinline__ void gload16(const void* g, void* l) {
  __builtin_amdgcn_global_load_lds((const __attribute__((address_space(1))) void*)g,
                                   (__attribute__((address_space(3))) void*)l, 16, 0, 0);
}

// ---------------- bf16 MFMA GEMM (r15 config — best measured, 530.9us total) ----------------
// BM=128, BN=64, BK=64, 512 thr (8 waves 8Mx1N, per-wave 16x64).
// TRIPLE-buffered LDS (3 x 24KB = 72KB -> 2 blocks/CU). Counted vmcnt:
// tile t+2 staged at step t; wait vmcnt(3) per step (t+1 stays in flight);
// vmcnt(0) only on final step. XOR-swizzled LDS (0 conflicts, verified).
__global__ __launch_bounds__(512, 4)
void k_gemm(const u16* __restrict__ A, int lda, ll sA, ll sA2,
            const u16* __restrict__ Bp, int ldb, ll sB, ll sB2,
            float* __restrict__ outF, u16* __restrict__ outB,
            int ldc, ll sC, ll sC2,
            u16* __restrict__ outBT, int ldt, ll sT, ll sT2,
            int K, int zdiv, const float* __restrict__ bias,
            const float* __restrict__ rowscale, int rscfrom,
            int splitcol, int act)
{
  constexpr int ABYT = 128 * 128;   // 16 KB
  constexpr int BBYT = 64 * 128;    // 8 KB
  constexpr int BUF = ABYT + BBYT;  // 24 KB
  const int z = blockIdx.z, zb = z / zdiv, zr = z - zb * zdiv;
  A  += (ll)zb * sA + (ll)zr * sA2;
  Bp += (ll)zb * sB + (ll)zr * sB2;
  const ll cof = (ll)zb * sC + (ll)zr * sC2;
  const ll tof = (ll)zb * sT + (ll)zr * sT2;
  const int bm = blockIdx.y * 128, bn = blockIdx.x * 64;
  __shared__ __align__(16) char lds[3 * BUF];   // 72 KB
  const int tid = threadIdx.x;
  const int lane = tid & 63, wid = tid >> 6;
  const int rowb = wid * 16;                    // 8 waves x 16 rows

  f32x4 acc[4];
  const f32x4 fz = {0.f, 0.f, 0.f, 0.f};
  #pragma unroll
  for (int j = 0; j < 4; ++j) acc[j] = fz;

  const int trow = tid >> 3;
  const int tg   = ((tid & 7) ^ (trow & 7)) * 8;
  const u16* gA  = A + (ll)(bm + trow) * lda + tg;
  const u16* gA2 = gA + (ll)64 * lda;
  const u16* gB  = Bp + (ll)(bn + trow) * ldb + tg;

  const int r = lane & 15, q = lane >> 4;
  const int c7 = r & 7;
  const int gs0 = ((q) ^ c7) << 4;
  const int gs1 = ((4 + q) ^ c7) << 4;
  const int aoff = (rowb + r) * 128;
  int boff[4];
  #pragma unroll
  for (int j = 0; j < 4; ++j) boff[j] = ABYT + (j * 16 + r) * 128;

  auto stage = [&](int buf, int it) {
    char* la = lds + buf * BUF + wid * 1024;
    char* lb = la + ABYT;
    const int ko = it << 6;
    gload16(gA + ko, la);
    gload16(gA2 + ko, la + 8192);
    gload16(gB + ko, lb);
  };

  const int nsteps = K >> 6;
  stage(0, 0);
  if (nsteps > 1) stage(1, 1);
  for (int it = 0; it < nsteps; ++it) {
    if (it == nsteps - 1) asm volatile("s_waitcnt vmcnt(0)" ::: "memory");
    else                  asm volatile("s_waitcnt vmcnt(3)" ::: "memory");
    __builtin_amdgcn_s_barrier();            // all waves' tile-t loads landed
    __builtin_amdgcn_sched_barrier(0);
    if (it + 2 < nsteps) {
      int nb = it + 2; while (nb >= 3) nb -= 3;
      stage(nb, it + 2);                     // WAR-safe: readers passed barrier
    }
    int p = it; while (p >= 3) p -= 3;
    const char* pa = lds + p * BUF;
    #pragma unroll
    for (int s = 0; s < 2; ++s) {
      const int gso = s ? gs1 : gs0;
      bf16x8 af = *(const bf16x8*)(pa + aoff + gso);
      bf16x8 bv[4];
      #pragma unroll
      for (int j = 0; j < 4; ++j) bv[j] = *(const bf16x8*)(pa + boff[j] + gso);
      #pragma unroll
      for (int j = 0; j < 4; ++j)
        acc[j] = __builtin_amdgcn_mfma_f32_16x16x32_bf16(af, bv[j], acc[j], 0, 0, 0);
    }
    asm volatile("s_waitcnt lgkmcnt(0)" ::: "memory");  // reads of buf[p] done
    __builtin_amdgcn_sched_barrier(0);
  }

  const int fr = lane & 15, fq = lane >> 4;
  const int r0 = bm + rowb + fq * 4;
  #pragma unroll
  for (int j = 0; j < 4; ++j) {
    const int cn = bn + j * 16 + fr;
    const float bvv = bias ? bias[cn] : 0.f;
    const bool doRs = rowscale && (cn >= rscfrom);
    float vv[4];
    #pragma unroll
    for (int t = 0; t < 4; ++t) {
      float v = acc[j][t] + bvv;
      if (doRs) v *= rowscale[r0 + t];
      if (act) v = 0.5f * v * (1.f + tanhf(0.7978845608028654f * (v + 0.044715f * v * v * v)));
      vv[t] = v;
    }
    if (cn < splitcol) {
      if (outF) {
        #pragma unroll
        for (int t = 0; t < 4; ++t) outF[cof + (ll)(r0 + t) * ldc + cn] = vv[t];
      }
      if (outB) {
        #pragma unroll
        for (int t = 0; t < 4; ++t) outB[cof + (ll)(r0 + t) * ldc + cn] = f2bf(vv[t]);
      }
    } else {
      u16x4 pk = {f2bf(vv[0]), f2bf(vv[1]), f2bf(vv[2]), f2bf(vv[3])};
      *(u16x4*)(outBT + tof + (ll)(cn - splitcol) * ldt + r0) = pk;
    }
  }
}

// ---------------- consolidated weight prep: 16 transposes in ONE dispatch ----------------
struct PrepTable {
  const float* src[16];
  u16* dst[16];
  int R[16];
  int C[16];
  int off[17];
};

__global__ __launch_bounds__(256)
void k_prep_all(PrepTable T)
{
  __shared__ float t[32][33];
  const int b = blockIdx.x;
  int w = 0;
  #pragma unroll
  for (int i = 1; i < 16; ++i) if (b >= T.off[i]) w = i;
  const int lb = b - T.off[w];
  const int tilesC = T.C[w] >> 5;
  const int by = (lb / tilesC) << 5;
  const int bx = (lb - (lb / tilesC) * tilesC) << 5;
  const float* in = T.src[w];
  u16* out = T.dst[w];
  const int R = T.R[w], C = T.C[w];
  const int tx = threadIdx.x & 31, ty = threadIdx.x >> 5;
  #pragma unroll
  for (int i = 0; i < 32; i += 8)
    t[ty + i][tx] = in[(ll)(by + ty + i) * C + bx + tx];
  __syncthreads();
  #pragma unroll
  for (int i = 0; i < 32; i += 8)
    out[(ll)(bx + ty + i) * R + by + tx] = f2bf(t[tx][ty + i]);
}

__global__ __launch_bounds__(256)
void k_cvt(const float* __restrict__ in, u16* __restrict__ out, int n)
{
  int i = blockIdx.x * 256 + threadIdx.x;
  if (i < n) out[i] = f2bf(in[i]);
}

__global__ __launch_bounds__(256)
void k_cat3f(float* __restrict__ dst, const float* __restrict__ a, int na,
             const float* __restrict__ b, int nb, const float* __restrict__ c, int nc)
{
  int i = blockIdx.x * 256 + threadIdx.x;
  if (i < na) dst[i] = a[i];
  else if (i < na + nb) dst[i] = b[i - na];
  else if (i < na + nb + nc) dst[i] = c[i - na - nb];
}

// ---------------- row softmax on bf16 in place (cols <= 1024) ----------------
__global__ __launch_bounds__(256)
void k_softmax_b16(u16* __restrict__ x, int cols, float scale)
{
  u16* p = x + (ll)blockIdx.x * cols;
  const int tid = threadIdx.x;
  __shared__ float red[256];
  float v[4];
  float m = -1e30f;
  #pragma unroll
  for (int i = 0; i < 4; ++i) {
    const int c = tid + (i << 8);
    v[i] = (c < cols) ? bf2f(p[c]) * scale : -1e30f;
    m = fmaxf(m, v[i]);
  }
  red[tid] = m; __syncthreads();
  for (int s = 128; s > 0; s >>= 1) { if (tid < s) red[tid] = fmaxf(red[tid], red[tid + s]); __syncthreads(); }
  m = red[0]; __syncthreads();
  float sum = 0.f;
  #pragma unroll
  for (int i = 0; i < 4; ++i) { v[i] = expf(v[i] - m); sum += v[i]; }
  red[tid] = sum; __syncthreads();
  for (int s = 128; s > 0; s >>= 1) { if (tid < s) red[tid] += red[tid + s]; __syncthreads(); }
  const float inv = 1.f / red[0];
  #pragma unroll
  for (int i = 0; i < 4; ++i) {
    const int c = tid + (i << 8);
    if (c < cols) p[c] = f2bf(v[i] * inv);
  }
}

// ---------------- layernorm: LN(x [+res][+res2][+rbias])*g + b ----------------
__global__ __launch_bounds__(256)
void k_layernorm(const float* __restrict__ x, const float* __restrict__ res,
                 const float* __restrict__ res2, const float* __restrict__ rbias,
                 const float* __restrict__ g, const float* __restrict__ b,
                 float* __restrict__ outF, u16* __restrict__ outB, int cols)
{
  const ll ro = (ll)blockIdx.x * cols;
  const float* px = x + ro;
  const float* pr = res ? res + ro : nullptr;
  const float* p2 = res2 ? res2 + ro : nullptr;
  __shared__ float red[256];
  const int tid = threadIdx.x;
  auto val = [&](int c) {
    float v = px[c];
    if (pr) v += pr[c];
    if (p2) v += p2[c];
    if (rbias) v += rbias[c];
    return v;
  };
  float s = 0.f;
  for (int c = tid; c < cols; c += 256) s += val(c);
  red[tid] = s; __syncthreads();
  for (int t = 128; t > 0; t >>= 1) { if (tid < t) red[tid] += red[tid + t]; __syncthreads(); }
  const float mean = red[0] / cols; __syncthreads();
  float s2 = 0.f;
  for (int c = tid; c < cols; c += 256) { float v = val(c) - mean; s2 += v * v; }
  red[tid] = s2; __syncthreads();
  for (int t = 128; t > 0; t >>= 1) { if (tid < t) red[tid] += red[tid + t]; __syncthreads(); }
  const float inv = rsqrtf(red[0] / cols + 1e-5f);
  for (int c = tid; c < cols; c += 256) {
    float v = (val(c) - mean) * inv * g[c] + b[c];
    if (outF) outF[ro + c] = v;
    if (outB) outB[ro + c] = f2bf(v);
  }
}

// ---- fused: henh = h + sigmoid(h.rgw+b0)*r; bb = bf16(LN(henh)*g+b) ----
// One block per row (cols==1024, 4 elems/thread held in registers).
__global__ __launch_bounds__(256)
void k_gate_add_ln(const float* __restrict__ h, const float* __restrict__ rr,
                   const float* __restrict__ w, const float* __restrict__ b0,
                   const float* __restrict__ g, const float* __restrict__ b,
                   float* __restrict__ outF, u16* __restrict__ outB)
{
  constexpr int C = 1024;
  const ll ro = (ll)blockIdx.x * C;
  const float* ph = h + ro;
  const float* pr = rr + ro;
  __shared__ float red[256];
  const int tid = threadIdx.x;
  float hv[4], rv[4];
  float s = 0.f;
  #pragma unroll
  for (int i = 0; i < 4; ++i) {
    const int c = tid + (i << 8);
    hv[i] = ph[c]; rv[i] = pr[c];
    s += hv[i] * w[c];
  }
  red[tid] = s; __syncthreads();
  for (int t = 128; t > 0; t >>= 1) { if (tid < t) red[tid] += red[tid + t]; __syncthreads(); }
  const float gate = 1.0f / (1.0f + expf(-(red[0] + b0[0])));
  __syncthreads();
  float vsum = 0.f;
  float vv[4];
  #pragma unroll
  for (int i = 0; i < 4; ++i) { vv[i] = hv[i] + gate * rv[i]; vsum += vv[i]; }
  red[tid] = vsum; __syncthreads();
  for (int t = 128; t > 0; t >>= 1) { if (tid < t) red[tid] += red[tid + t]; __syncthreads(); }
  const float mean = red[0] / C; __syncthreads();
  float v2 = 0.f;
  #pragma unroll
  for (int i = 0; i < 4; ++i) { float d = vv[i] - mean; v2 += d * d; }
  red[tid] = v2; __syncthreads();
  for (int t = 128; t > 0; t >>= 1) { if (tid < t) red[tid] += red[tid + t]; __syncthreads(); }
  const float inv = rsqrtf(red[0] / C + 1e-5f);
  #pragma unroll
  for (int i = 0; i < 4; ++i) {
    const int c = tid + (i << 8);
    outF[ro + c] = vv[i];
    outB[ro + c] = f2bf((vv[i] - mean) * inv * g[c] + b[c]);
  }
}

__global__ __launch_bounds__(256)
void k_gate(const float* __restrict__ x, const float* __restrict__ w,
            const float* __restrict__ b0, float* __restrict__ out, int cols)
{
  const int lane = threadIdx.x & 63;
  const int wv = threadIdx.x >> 6;
  const ll row = (ll)blockIdx.x * 4 + wv;
  const float* p = x + row * cols;
  float s = 0.f;
  for (int c = lane; c < cols; c += 64) s += p[c] * w[c];
  #pragma unroll
  for (int off = 32; off > 0; off >>= 1) s += __shfl_down(s, off);
  if (lane == 0) out[row] = 1.0f / (1.0f + expf(-(s + b0[0])));
}

// ---------------- elementwise ----------------
__global__ __launch_bounds__(256)
void k_combine2(float* __restrict__ oF, u16* __restrict__ oB,
                const float* __restrict__ a, float sa, const float* __restrict__ b,
                const float* __restrict__ emb, int n, int Dm1)
{
  int i = blockIdx.x * 256 + threadIdx.x;
  if (i >= n) return;
  float v = sa * a[i];
  if (b) v += b[i];
  v += emb[i & Dm1];
  oF[i] = v; oB[i] = f2bf(v);
}

__global__ __launch_bounds__(256)
void k_add2(float* __restrict__ oF, u16* __restrict__ oB,
            const float* __restrict__ a, const float* __restrict__ b, int n)
{
  int i = blockIdx.x * 256 + threadIdx.x;
  if (i >= n) return;
  float v = a[i] + b[i];
  oF[i] = v; oB[i] = f2bf(v);
}

// ---------------- host ----------------
extern "C" void kernel_launch(void* const* d_in, const int* in_sizes, int n_in,
                              void* d_out, int out_size, void* d_ws, size_t ws_size,
                              hipStream_t stream)
{
  (void)in_sizes; (void)n_in; (void)out_size;
  const float* x        = (const float*)d_in[0];
  const float* cache0   = (const float*)d_in[1];
  const float* iter_emb = (const float*)d_in[2];
  const float* rq_w     = (const float*)d_in[3];
  const float* rg_w     = (const float*)d_in[4];
  const float* rg_b     = (const float*)d_in[5];
  const float* ck_w     = (const float*)d_in[6];
  const float* cv_w     = (const float*)d_in[7];
  const float* aq_w     = (const float*)d_in[8];
  const float* ak_w     = (const float*)d_in[9];
  const float* av_w     = (const float*)d_in[10];
  const float* ao_w     = (const float*)d_in[11];
  const float* aq_b     = (const float*)d_in[12];
  const float* ak_b     = (const float*)d_in[13];
  const float* av_b     = (const float*)d_in[14];
  const float* ao_b     = (const float*)d_in[15];
  const float* f1_w     = (const float*)d_in[16];
  const float* f1_b     = (const float*)d_in[17];
  const float* f2_w     = (const float*)d_in[18];
  const float* f2_b     = (const float*)d_in[19];
  const float* n1_g     = (const float*)d_in[20];
  const float* n1_b     = (const float*)d_in[21];
  const float* n2_g     = (const float*)d_in[22];
  const float* n2_b     = (const float*)d_in[23];
  const float* sq_w     = (const float*)d_in[24];
  const float* tk_w     = (const float*)d_in[25];
  const float* tv_w     = (const float*)d_in[26];
  const float* wg_w     = (const float*)d_in[27];
  const float* wg_b     = (const float*)d_in[28];
  const float* cq_w     = (const float*)d_in[29];
  const float* ck2_w    = (const float*)d_in[30];
  const float* cv2_w    = (const float*)d_in[31];
  const float* co_w     = (const float*)d_in[32];
  const float* cq_b     = (const float*)d_in[33];
  const float* ck2_b    = (const float*)d_in[34];
  const float* cv2_b    = (const float*)d_in[35];
  const float* co_b     = (const float*)d_in[36];
  const float* cn_g     = (const float*)d_in[37];
  const float* cn_b     = (const float*)d_in[38];
  // d_in[39] = max_iterations (fixed 2; schedule hardcoded for graph capture)

  float* out = (float*)d_out;

  // -------- workspace carve --------
  size_t off = 0;
  char* base = (char*)d_ws;
  auto allocF = [&](size_t n) { float* p = (float*)(base + off); off += n * 4; off = (off + 255) & ~(size_t)255; return p; };
  auto allocH = [&](size_t n) { u16* p = (u16*)(base + off); off += n * 2; off = (off + 255) & ~(size_t)255; return p; };

  float* hbuf  = allocF((size_t)BS_ * D_);
  float* henh  = allocF((size_t)BS_ * D_);
  float* hcomp = allocF((size_t)BS_ * D_);
  float* h2b   = allocF((size_t)BS_ * D_);
  float* tA    = allocF((size_t)2 * BS_ * D_);
  float* gate  = allocF((size_t)BS_);
  float* ccnf  = allocF((size_t)BNS_ * DS_);
  float* updf  = allocF((size_t)BNS_ * DS_);
  float* coo   = allocF((size_t)BNS_ * DS_);
  float* ccwf  = allocF((size_t)BNS_ * DS_);
  float* qkvb  = allocF(3 * D_);
  float* cqkvb = allocF(3 * DS_);
  u16* rqT  = allocH((size_t)D_ * D_);
  u16* ckT  = allocH((size_t)D_ * DS_);
  u16* cvT  = allocH((size_t)D_ * DS_);
  u16* aqT  = allocH((size_t)D_ * D_);
  u16* akT  = allocH((size_t)D_ * D_);
  u16* avT  = allocH((size_t)D_ * D_);
  u16* aoT  = allocH((size_t)D_ * D_);
  u16* f1T  = allocH((size_t)DFF_ * D_);
  u16* f2T  = allocH((size_t)D_ * DFF_);
  u16* sqT  = allocH((size_t)DS_ * DS_);
  u16* tkT  = allocH((size_t)DS_ * D_);
  u16* tvTw = allocH((size_t)DS_ * D_);
  u16* cqT  = allocH((size_t)DS_ * DS_);
  u16* ck2T = allocH((size_t)DS_ * DS_);
  u16* cv2T = allocH((size_t)DS_ * DS_);
  u16* coT  = allocH((size_t)DS_ * DS_);
  u16* bb1  = allocH((size_t)BS_ * D_);
  u16* bb2  = allocH((size_t)BS_ * D_);
  u16* bb3  = allocH((size_t)BS_ * D_);
  u16* bb4  = allocH((size_t)BS_ * D_);
  u16* bb5  = allocH((size_t)B_ * H_ * S_ * S_);
  u16* bbQK = allocH((size_t)BS_ * 2 * D_);
  u16* bbCQK= allocH((size_t)BNS_ * 2 * DS_);
  u16* cc0b = allocH((size_t)BNS_ * DS_);
  u16* ccwb = allocH((size_t)BNS_ * DS_);
  u16* sqb  = allocH((size_t)BNS_ * DS_);
  u16* tkb  = allocH((size_t)BS_ * DS_);
  u16* tvTb = allocH((size_t)DS_ * BS_);
  u16* ccnb = allocH((size_t)BNS_ * DS_);
  u16* cv2Tb= allocH((size_t)DS_ * BNS_);
  u16* csab = allocH((size_t)BNS_ * DS_);
  if (off > ws_size) return;
  (void)cvT; (void)akT; (void)avT; (void)tvTw; (void)ck2T; (void)cv2T;

  auto gemm = [&](int M, int N, int K, int z, int zdiv,
                  const u16* Ap, int lda, ll sa, ll sa2,
                  const u16* Bq, int ldb, ll sb, ll sb2,
                  float* oF, u16* oB, int ldc, ll sc, ll sc2,
                  u16* oBT, int ldt, ll st, ll st2,
                  const float* bias, const float* rsc, int rscfrom,
                  int splitcol, int act) {
    dim3 g(N / 64, M / 128, z);
    k_gemm<<<g, 512, 0, stream>>>(Ap, lda, sa, sa2, Bq, ldb, sb, sb2,
        oF, oB, ldc, sc, sc2, oBT, ldt, st, st2, K, zdiv, bias, rsc, rscfrom, splitcol, act);
  };
  auto lnorm = [&](const float* xp, const float* rp, const float* rp2, const float* rb,
                   const float* g, const float* b, float* oF, u16* oB, int rows, int cols) {
    k_layernorm<<<rows, 256, 0, stream>>>(xp, rp, rp2, rb, g, b, oF, oB, cols);
  };
  auto eg = [](int n) { return dim3((n + 255) / 256); };

  // ---- weight prep: ONE dispatch for all 16 transposes ----
  {
    PrepTable T;
    const float* srcs[16] = {rq_w, ck_w, cv_w, aq_w, ak_w, av_w, ao_w, f1_w,
                             f2_w, sq_w, tk_w, tv_w, cq_w, ck2_w, cv2_w, co_w};
    u16* dsts[16] = {rqT, ckT, cvT, aqT, akT, avT, aoT, f1T,
                     f2T, sqT, tkT, tvTw, cqT, ck2T, cv2T, coT};
    const int Rs[16] = {D_, DS_, DS_, D_, D_, D_, D_, D_, DFF_, DS_, D_, D_, DS_, DS_, DS_, DS_};
    const int Cs[16] = {D_, D_, D_, D_, D_, D_, D_, DFF_, D_, DS_, DS_, DS_, DS_, DS_, DS_, DS_};
    int acc0 = 0;
    for (int i = 0; i < 16; ++i) {
      T.src[i] = srcs[i]; T.dst[i] = dsts[i]; T.R[i] = Rs[i]; T.C[i] = Cs[i];
      T.off[i] = acc0;
      acc0 += (Rs[i] >> 5) * (Cs[i] >> 5);
    }
    T.off[16] = acc0;
    k_prep_all<<<acc0, 256, 0, stream>>>(T);
  }
  k_cvt<<<eg(BNS_ * DS_), 256, 0, stream>>>(cache0, cc0b, BNS_ * DS_);
  k_cat3f<<<eg(3 * D_), 256, 0, stream>>>(qkvb, aq_b, D_, ak_b, D_, av_b, D_);
  k_cat3f<<<eg(3 * DS_), 256, 0, stream>>>(cqkvb, cq_b, DS_, ck2_b, DS_, cv2_b, DS_);

  // ---- mem_read: ends with fused gate+add+LN1 -> henh (fp32) + bb1 (bf16 LN) ----
  auto mem_read = [&](const float* h_f, const u16* h_b, const u16* cc_b, float* o_henh) {
    gemm(BS_, D_, D_, 1, 1, h_b, D_, 0, 0, rqT, D_, 0, 0,
         nullptr, bb2, D_, 0, 0, nullptr, 0, 0, 0,
         nullptr, nullptr, 0, D_, 0);                                               // q
    gemm(BNS_, 2 * D_, DS_, 1, 1, cc_b, DS_, 0, 0, ckT, DS_, 0, 0,
         nullptr, bb3, D_, 0, 0, bb4, BNS_, 0, 0,
         nullptr, nullptr, 0, D_, 0);                                               // k|v^T fused
    gemm(S_, NSLOT_, D_, B_, 1, bb2, D_, (ll)S_ * D_, 0,
         bb3, D_, (ll)NSLOT_ * D_, 0,
         nullptr, bb5, NSLOT_, (ll)S_ * NSLOT_, 0, nullptr, 0, 0, 0,
         nullptr, nullptr, 0, NSLOT_, 0);                                           // q k^T
    k_softmax_b16<<<B_ * S_, 256, 0, stream>>>(bb5, NSLOT_, 0.03125f);
    gemm(S_, D_, NSLOT_, B_, 1, bb5, NSLOT_, (ll)S_ * NSLOT_, 0,
         bb4, BNS_, NSLOT_, 0,
         tA, nullptr, D_, (ll)S_ * D_, 0, nullptr, 0, 0, 0,
         nullptr, nullptr, 0, D_, 0);                                               // readout
    k_gate_add_ln<<<BS_, 256, 0, stream>>>(h_f, tA, rg_w, rg_b, n1_g, n1_b,
                                           o_henh, bb1);                            // henh + LN1(bf16)
  };

  // ---- compute_block (bb1 = LN1(henh) already prepared by mem_read) ----
  auto compute_block = [&](const float* he, float* oF, u16* oB) {
    gemm(BS_, 3 * D_, D_, 1, 1, bb1, D_, 0, 0, aqT, D_, 0, 0,
         nullptr, bbQK, 2 * D_, 0, 0, bb4, BS_, 0, 0,
         qkvb, nullptr, 0, 2 * D_, 0);                                              // qkv fused (va^T->bb4)
    gemm(S_, S_, HD_, B_ * H_, H_,
         bbQK, 2 * D_, (ll)S_ * 2 * D_, HD_,
         bbQK + D_, 2 * D_, (ll)S_ * 2 * D_, HD_,
         nullptr, bb5, S_, (ll)H_ * S_ * S_, (ll)S_ * S_, nullptr, 0, 0, 0,
         nullptr, nullptr, 0, S_, 0);                                               // scores
    k_softmax_b16<<<B_ * H_ * S_, 256, 0, stream>>>(bb5, S_, 0.0625f);
    gemm(S_, HD_, S_, B_ * H_, H_,
         bb5, S_, (ll)H_ * S_ * S_, (ll)S_ * S_,
         bb4, BS_, S_, (ll)HD_ * BS_,
         nullptr, bb2, D_, (ll)S_ * D_, HD_, nullptr, 0, 0, 0,
         nullptr, nullptr, 0, HD_, 0);                                              // attnv
    gemm(BS_, D_, D_, 1, 1, bb2, D_, 0, 0, aoT, D_, 0, 0,
         tA, nullptr, D_, 0, 0, nullptr, 0, 0, 0,
         ao_b, nullptr, 0, D_, 0);                                                  // attno
    lnorm(he, tA, nullptr, nullptr, n1_g, n1_b, h2b, bb1, BS_, D_);                 // h2
    gemm(BS_, DFF_, D_, 1, 1, bb1, D_, 0, 0, f1T, D_, 0, 0,
         nullptr, bb5, DFF_, 0, 0, nullptr, 0, 0, 0,
         f1_b, nullptr, 0, DFF_, 1);                                                // f1+gelu
    gemm(BS_, D_, 2048, 2, 2, bb5, DFF_, 0, 2048, f2T, DFF_, 0, 2048,
         tA, nullptr, D_, 0, (ll)BS_ * D_, nullptr, 0, 0, 0,
         nullptr, nullptr, 0, D_, 0);                                               // f2 split-K=2
    lnorm(h2b, tA, tA + (ll)BS_ * D_, f2_b, n2_g, n2_b, oF, oB, BS_, D_);           // LN(h2+p0+p1+f2_b)
  };

  // ---- mem_write + cache self-attn (skipped in last iter) ----
  auto mem_write_csa = [&](const float* hc_f, const u16* hc_b,
                           const float* ccin_f, const u16* ccin_b) {
    gemm(BNS_, DS_, DS_, 1, 1, ccin_b, DS_, 0, 0, sqT, DS_, 0, 0,
         nullptr, sqb, DS_, 0, 0, nullptr, 0, 0, 0,
         nullptr, nullptr, 0, DS_, 0);                                              // sq
    k_gate<<<BS_ / 4, 256, 0, stream>>>(hc_f, wg_w, wg_b, gate, D_);
    gemm(BS_, 2 * DS_, D_, 1, 1, hc_b, D_, 0, 0, tkT, D_, 0, 0,
         nullptr, tkb, DS_, 0, 0, tvTb, BS_, 0, 0,
         nullptr, gate, DS_, DS_, 0);                                               // tk | (gate*tv)^T
    gemm(NSLOT_, S_, DS_, B_, 1, sqb, DS_, (ll)NSLOT_ * DS_, 0,
         tkb, DS_, (ll)S_ * DS_, 0,
         nullptr, bb5, S_, (ll)NSLOT_ * S_, 0, nullptr, 0, 0, 0,
         nullptr, nullptr, 0, S_, 0);                                               // slot scores
    k_softmax_b16<<<B_ * NSLOT_, 256, 0, stream>>>(bb5, S_, 0.05590169943749474f);
    gemm(NSLOT_, DS_, S_, B_, 1, bb5, S_, (ll)NSLOT_ * S_, 0,
         tvTb, BS_, S_, 0,
         updf, nullptr, DS_, (ll)NSLOT_ * DS_, 0, nullptr, 0, 0, 0,
         nullptr, nullptr, 0, DS_, 0);                                              // upd
    k_add2<<<eg(BNS_ * DS_), 256, 0, stream>>>(ccnf, ccnb, ccin_f, updf, BNS_ * DS_);
    gemm(BNS_, 3 * DS_, DS_, 1, 1, ccnb, DS_, 0, 0, cqT, DS_, 0, 0,
         nullptr, bbCQK, 2 * DS_, 0, 0, cv2Tb, BNS_, 0, 0,
         cqkvb, nullptr, 0, 2 * DS_, 0);                                            // cq|ck|cv^T fused
    gemm(NSLOT_, NSLOT_, CHD_, B_ * CH_, CH_,
         bbCQK, 2 * DS_, (ll)NSLOT_ * 2 * DS_, CHD_,
         bbCQK + DS_, 2 * DS_, (ll)NSLOT_ * 2 * DS_, CHD_,
         nullptr, bb5, NSLOT_, (ll)CH_ * NSLOT_ * NSLOT_, (ll)NSLOT_ * NSLOT_,
         nullptr, 0, 0, 0, nullptr, nullptr, 0, NSLOT_, 0);                         // csa scores
    k_softmax_b16<<<B_ * CH_ * NSLOT_, 256, 0, stream>>>(bb5, NSLOT_, 0.125f);
    gemm(NSLOT_, CHD_, NSLOT_, B_ * CH_, CH_,
         bb5, NSLOT_, (ll)CH_ * NSLOT_ * NSLOT_, (ll)NSLOT_ * NSLOT_,
         cv2Tb, BNS_, NSLOT_, (ll)CHD_ * BNS_,
         nullptr, csab, DS_, (ll)NSLOT_ * DS_, CHD_, nullptr, 0, 0, 0,
         nullptr, nullptr, 0, CHD_, 0);                                             // csa pv
    gemm(BNS_, DS_, DS_, 1, 1, csab, DS_, 0, 0, coT, DS_, 0, 0,
         coo, nullptr, DS_, 0, 0, nullptr, 0, 0, 0,
         co_b, nullptr, 0, DS_, 0);                                                 // co
    lnorm(ccnf, coo, nullptr, nullptr, cn_g, cn_b, ccwf, ccwb, BNS_, DS_);
  };

  // ================= iteration 0 =================
  k_combine2<<<eg(BS_ * D_), 256, 0, stream>>>(hbuf, bb1, x, 1.0f, nullptr, iter_emb, BS_ * D_, D_ - 1);
  mem_read(hbuf, bb1, cc0b, henh);
  compute_block(henh, hcomp, bb3);
  mem_write_csa(hcomp, bb3, cache0, cc0b);

  // ================= iteration 1 (last: cache update dead, skipped) =================
  k_combine2<<<eg(BS_ * D_), 256, 0, stream>>>(hbuf, bb1, hcomp, 2.0f, x, iter_emb + D_, BS_ * D_, D_ - 1);
  mem_read(hbuf, bb1, ccwb, henh);
  compute_block(henh, out, nullptr);
}